// Round 1
// baseline (387.634 us; speedup 1.0000x reference)
//
#include <hip/hip_runtime.h>
#include <math.h>

constexpr int B_  = 2;
constexpr int N_  = 10000;
constexpr int E_  = 160000;
constexpr int H_  = 128;
constexpr int ET_ = 8;
constexpr float EPS_ = 1e-5f;
constexpr float RSQH = 0.08838834764831845f; // 1/sqrt(128)

// ---------------------------------------------------------------------------
// Per-node Q/K/V projections.  Q[b,n] = (h+t)@Wq (+bq), K[b,n] = (h+t)@Wk,
// V[b,n] = h@Wv.  NT nodes per 128-thread block; W streamed from L2 once per
// block (196KB*3 per block amortized over NT nodes).
// ---------------------------------------------------------------------------
template<int NT>
__global__ __launch_bounds__(128)
void qkv_kernel(const float* __restrict__ hidden, const float* __restrict__ time_emb,
                const float* __restrict__ Wq, const float* __restrict__ bq,
                const float* __restrict__ Wk, const float* __restrict__ Wv,
                float* __restrict__ Q, float* __restrict__ K, float* __restrict__ V)
{
    __shared__ float x1[NT][H_];   // hidden + time
    __shared__ float x2[NT][H_];   // hidden
    const int base = blockIdx.x * NT;
    const int tid = threadIdx.x;
    for (int idx = tid; idx < NT * H_; idx += 128) {
        int m = idx >> 7, d = idx & (H_ - 1);
        int node = base + m;
        float hv = hidden[node * H_ + d];
        float tv = time_emb[node * H_ + d];
        x1[m][d] = hv + tv;
        x2[m][d] = hv;
    }
    __syncthreads();
    const int j = tid;
    float aq[NT], ak[NT], av[NT];
#pragma unroll
    for (int m = 0; m < NT; ++m) { aq[m] = 0.f; ak[m] = 0.f; av[m] = 0.f; }
    for (int d = 0; d < H_; d += 4) {
        float wq0 = Wq[(d+0)*H_ + j], wq1 = Wq[(d+1)*H_ + j];
        float wq2 = Wq[(d+2)*H_ + j], wq3 = Wq[(d+3)*H_ + j];
        float wk0 = Wk[(d+0)*H_ + j], wk1 = Wk[(d+1)*H_ + j];
        float wk2 = Wk[(d+2)*H_ + j], wk3 = Wk[(d+3)*H_ + j];
        float wv0 = Wv[(d+0)*H_ + j], wv1 = Wv[(d+1)*H_ + j];
        float wv2 = Wv[(d+2)*H_ + j], wv3 = Wv[(d+3)*H_ + j];
#pragma unroll
        for (int m = 0; m < NT; ++m) {
            float4 a = *(const float4*)&x1[m][d];
            float4 b = *(const float4*)&x2[m][d];
            aq[m] += a.x*wq0 + a.y*wq1 + a.z*wq2 + a.w*wq3;
            ak[m] += a.x*wk0 + a.y*wk1 + a.z*wk2 + a.w*wk3;
            av[m] += b.x*wv0 + b.y*wv1 + b.z*wv2 + b.w*wv3;
        }
    }
    float bqj = bq[j];
#pragma unroll
    for (int m = 0; m < NT; ++m) {
        int node = base + m;
        Q[node*H_ + j] = aq[m] + bqj;
        K[node*H_ + j] = ak[m];
        V[node*H_ + j] = av[m];
    }
}

// ---------------------------------------------------------------------------
// Per-edge-type tables: Kt[t] = edge_emb[t]@Wk + bk, Vt[t] = edge_emb[t]@Wv + bv,
// eb[t] = edge_emb[t]@We + be.  ET=8 -> trivial.
// ---------------------------------------------------------------------------
__global__ __launch_bounds__(128)
void edgetab_kernel(const float* __restrict__ edge_emb,
                    const float* __restrict__ Wk, const float* __restrict__ bk,
                    const float* __restrict__ Wv, const float* __restrict__ bv,
                    const float* __restrict__ We, const float* __restrict__ be,
                    float* __restrict__ Kt, float* __restrict__ Vt, float* __restrict__ eb)
{
    const int j = threadIdx.x;
    for (int t = 0; t < ET_; ++t) {
        float ak = bk[j], av = bv[j];
        for (int d = 0; d < H_; ++d) {
            float e = edge_emb[t*H_ + d];
            ak += e * Wk[d*H_ + j];
            av += e * Wv[d*H_ + j];
        }
        Kt[t*H_ + j] = ak;
        Vt[t*H_ + j] = av;
    }
    if (j < ET_) {
        float s = be[0];
        for (int d = 0; d < H_; ++d) s += edge_emb[j*H_ + d] * We[d];
        eb[j] = s;
    }
}

// ---------------------------------------------------------------------------
// CSR build: histogram of tgt, exclusive scan, scatter (counting sort).
// sorted[] packs src | (type<<16).
// ---------------------------------------------------------------------------
__global__ void hist_kernel(const int* __restrict__ tgt, int* __restrict__ hist)
{
    int e = blockIdx.x * blockDim.x + threadIdx.x;
    if (e < E_) atomicAdd(&hist[tgt[e]], 1);
}

__global__ __launch_bounds__(1024)
void scan_kernel(const int* __restrict__ hist, int* __restrict__ offs, int* __restrict__ cursor)
{
    __shared__ int tmp[1024];
    __shared__ int carry_s;
    const int tid = threadIdx.x;
    if (tid == 0) carry_s = 0;
    __syncthreads();
    for (int base = 0; base < N_; base += 1024) {
        int v = (base + tid < N_) ? hist[base + tid] : 0;
        tmp[tid] = v;
        __syncthreads();
        for (int off = 1; off < 1024; off <<= 1) {
            int t = (tid >= off) ? tmp[tid - off] : 0;
            __syncthreads();
            tmp[tid] += t;
            __syncthreads();
        }
        int incl = tmp[tid];
        int carry = carry_s;
        if (base + tid < N_) {
            int excl = carry + incl - v;
            offs[base + tid] = excl;
            cursor[base + tid] = excl;
        }
        __syncthreads();
        if (tid == 1023) carry_s = carry + incl;
        __syncthreads();
    }
    if (tid == 0) offs[N_] = carry_s;
}

__global__ void scatter_kernel(const int* __restrict__ src, const int* __restrict__ tgt,
                               const int* __restrict__ type, int* __restrict__ cursor,
                               int* __restrict__ sorted)
{
    int e = blockIdx.x * blockDim.x + threadIdx.x;
    if (e < E_) {
        int t = tgt[e];
        int pos = atomicAdd(&cursor[t], 1);
        sorted[pos] = src[e] | (type[e] << 16);
    }
}

// ---------------------------------------------------------------------------
// Per (b, target-node) attention: online softmax over incoming edges.
// Block = 128 threads = 2 waves; each wave streams alternate edges with its
// own running (m, l, acc) state over 64 lanes x float2; merged via LDS.
// ---------------------------------------------------------------------------
__global__ __launch_bounds__(128)
void attn_kernel(const float* __restrict__ Q, const float* __restrict__ K,
                 const float* __restrict__ V, const float* __restrict__ Kt,
                 const float* __restrict__ Vt, const float* __restrict__ eb,
                 const int* __restrict__ offs, const int* __restrict__ sorted,
                 float* __restrict__ agg)
{
    const int bn = blockIdx.x;            // b*N + n
    const int b = bn / N_;
    const int n = bn - b * N_;
    const int tid = threadIdx.x;
    const int wave = tid >> 6, lane = tid & 63;
    const int beg = offs[n], end = offs[n + 1];
    const int bbase = b * N_;

    const float2 q2 = *(const float2*)&Q[bn * H_ + 2 * lane];
    float m = -INFINITY, l = 0.f;
    float accx = 0.f, accy = 0.f;

    for (int i = beg + wave; i < end; i += 2) {
        int pk = sorted[i];
        int s = pk & 0xFFFF, t = pk >> 16;
        const float2 k2  = *(const float2*)&K[(bbase + s) * H_ + 2 * lane];
        const float2 kt2 = *(const float2*)&Kt[t * H_ + 2 * lane];
        float part = q2.x * (k2.x + kt2.x) + q2.y * (k2.y + kt2.y);
#pragma unroll
        for (int off = 32; off; off >>= 1) part += __shfl_xor(part, off);
        float logit = part * RSQH + eb[t];
        float nm = fmaxf(m, logit);
        float scale = __expf(m - nm);      // m=-inf on first edge -> 0
        float p = __expf(logit - nm);
        l = l * scale + p;
        const float2 v2  = *(const float2*)&V[(bbase + s) * H_ + 2 * lane];
        const float2 vt2 = *(const float2*)&Vt[t * H_ + 2 * lane];
        accx = accx * scale + p * (v2.x + vt2.x);
        accy = accy * scale + p * (v2.y + vt2.y);
        m = nm;
    }

    __shared__ float sm[2], sl[2];
    __shared__ float sacc[2][H_];
    if (lane == 0) { sm[wave] = m; sl[wave] = l; }
    sacc[wave][2 * lane]     = accx;
    sacc[wave][2 * lane + 1] = accy;
    __syncthreads();

    float outv;
    if (end == beg) {
        outv = 0.f;                        // empty segment -> aggregated = 0
    } else {
        float m0 = sm[0], m1 = sm[1];
        float nm = fmaxf(m0, m1);
        float s0 = __expf(m0 - nm), s1 = __expf(m1 - nm);   // exp(-inf)=0 ok
        float L = sl[0] * s0 + sl[1] * s1;
        outv = (sacc[0][tid] * s0 + sacc[1][tid] * s1) / L;
    }
    agg[bn * H_ + tid] = outv;
}

// ---------------------------------------------------------------------------
// MLP (cat@W1 -> silu -> @W2) + residual + LayerNorm.  NT nodes per block so
// W1 (196KB) streams from L2 once per NT nodes.
// ---------------------------------------------------------------------------
template<int NT>
__global__ __launch_bounds__(128)
void mlp_ln_kernel(const float* __restrict__ hidden, const float* __restrict__ agg,
                   const float* __restrict__ time_emb,
                   const float* __restrict__ W1, const float* __restrict__ b1,
                   const float* __restrict__ W2, const float* __restrict__ b2,
                   const float* __restrict__ gamma, const float* __restrict__ beta,
                   float* __restrict__ out)
{
    __shared__ float cat_s[NT][3 * H_];
    __shared__ float h1_s[NT][H_];
    __shared__ float x_s[NT][H_];
    const int base = blockIdx.x * NT;
    const int tid = threadIdx.x;
    for (int m = 0; m < NT; ++m) {
        int node = base + m;
        cat_s[m][tid]          = hidden[node * H_ + tid];
        cat_s[m][H_ + tid]     = agg[node * H_ + tid];
        cat_s[m][2 * H_ + tid] = time_emb[node * H_ + tid];
    }
    __syncthreads();
    const int j = tid;
    float a1[NT];
    const float b1j = b1[j];
#pragma unroll
    for (int m = 0; m < NT; ++m) a1[m] = b1j;
    for (int d = 0; d < 3 * H_; d += 4) {
        float w0 = W1[(d+0)*H_ + j], w1 = W1[(d+1)*H_ + j];
        float w2 = W1[(d+2)*H_ + j], w3 = W1[(d+3)*H_ + j];
#pragma unroll
        for (int m = 0; m < NT; ++m) {
            float4 c = *(const float4*)&cat_s[m][d];
            a1[m] += c.x*w0 + c.y*w1 + c.z*w2 + c.w*w3;
        }
    }
#pragma unroll
    for (int m = 0; m < NT; ++m) {
        float v = a1[m];
        h1_s[m][j] = v / (1.f + __expf(-v));   // silu
    }
    __syncthreads();
    float a2[NT];
    const float b2j = b2[j];
#pragma unroll
    for (int m = 0; m < NT; ++m) a2[m] = b2j;
    for (int d = 0; d < H_; d += 4) {
        float w0 = W2[(d+0)*H_ + j], w1 = W2[(d+1)*H_ + j];
        float w2 = W2[(d+2)*H_ + j], w3 = W2[(d+3)*H_ + j];
#pragma unroll
        for (int m = 0; m < NT; ++m) {
            float4 h = *(const float4*)&h1_s[m][d];
            a2[m] += h.x*w0 + h.y*w1 + h.z*w2 + h.w*w3;
        }
    }
#pragma unroll
    for (int m = 0; m < NT; ++m) x_s[m][j] = cat_s[m][j] + a2[m];  // residual (cat[0:128]=hidden)
    __syncthreads();

    const int wave = tid >> 6, lane = tid & 63;
    for (int m = wave * (NT / 2); m < (wave + 1) * (NT / 2); ++m) {
        float xa = x_s[m][lane], xb = x_s[m][lane + 64];
        float s = xa + xb, sq = xa * xa + xb * xb;
#pragma unroll
        for (int off = 32; off; off >>= 1) {
            s  += __shfl_xor(s, off);
            sq += __shfl_xor(sq, off);
        }
        float mu  = s * (1.f / H_);
        float var = sq * (1.f / H_) - mu * mu;
        float rs  = rsqrtf(var + EPS_);
        int node = base + m;
        out[node*H_ + lane]      = (xa - mu) * rs * gamma[lane]      + beta[lane];
        out[node*H_ + lane + 64] = (xb - mu) * rs * gamma[lane + 64] + beta[lane + 64];
    }
}

// ---------------------------------------------------------------------------
extern "C" void kernel_launch(void* const* d_in, const int* in_sizes, int n_in,
                              void* d_out, int out_size, void* d_ws, size_t ws_size,
                              hipStream_t stream)
{
    const float* hidden   = (const float*)d_in[0];
    const float* time_emb = (const float*)d_in[1];
    const int*   eidx     = (const int*)d_in[2];
    const int*   etype    = (const int*)d_in[3];
    const float* edge_emb = (const float*)d_in[4];
    const float* Wq = (const float*)d_in[5];
    const float* bq = (const float*)d_in[6];
    const float* Wk = (const float*)d_in[7];
    const float* bk = (const float*)d_in[8];
    const float* Wv = (const float*)d_in[9];
    const float* bv = (const float*)d_in[10];
    const float* We = (const float*)d_in[11];
    const float* be = (const float*)d_in[12];
    const float* W1 = (const float*)d_in[13];
    const float* b1 = (const float*)d_in[14];
    const float* W2 = (const float*)d_in[15];
    const float* b2 = (const float*)d_in[16];
    const float* gamma = (const float*)d_in[17];
    const float* beta  = (const float*)d_in[18];
    float* out = (float*)d_out;

    constexpr int BNH = B_ * N_ * H_;
    float* Q   = (float*)d_ws;
    float* K   = Q + BNH;
    float* V   = K + BNH;
    float* agg = V + BNH;
    float* Kt  = agg + BNH;
    float* Vt  = Kt + ET_ * H_;
    float* ebt = Vt + ET_ * H_;
    int* hist   = (int*)(ebt + ET_);
    int* offs   = hist + N_;
    int* cursor = offs + (N_ + 1);
    int* sorted = cursor + N_;

    const int* esrc = eidx;
    const int* etgt = eidx + E_;

    hipMemsetAsync(hist, 0, N_ * sizeof(int), stream);

    qkv_kernel<16><<<(B_ * N_) / 16, 128, 0, stream>>>(hidden, time_emb, Wq, bq, Wk, Wv, Q, K, V);
    edgetab_kernel<<<1, 128, 0, stream>>>(edge_emb, Wk, bk, Wv, bv, We, be, Kt, Vt, ebt);
    hist_kernel<<<(E_ + 255) / 256, 256, 0, stream>>>(etgt, hist);
    scan_kernel<<<1, 1024, 0, stream>>>(hist, offs, cursor);
    scatter_kernel<<<(E_ + 255) / 256, 256, 0, stream>>>(esrc, etgt, etype, cursor, sorted);
    attn_kernel<<<B_ * N_, 128, 0, stream>>>(Q, K, V, Kt, Vt, ebt, offs, sorted, agg);
    mlp_ln_kernel<16><<<(B_ * N_) / 16, 128, 0, stream>>>(hidden, agg, time_emb, W1, b1, W2, b2, gamma, beta, out);
}